// Round 2
// baseline (422.385 us; speedup 1.0000x reference)
//
#include <hip/hip_runtime.h>
#include <math.h>

#define N_CH 17
#define IN_H 64
#define IN_W 32
#define OUT_H 16
#define OUT_W 8
#define HW 128

// per-wave LDS region:
//   s_in: 68 rows x 32 cols (rows 0,1,66,67 are zero pads; data rows 2..65)
//   tmp : 16 rows x 37 stride (cols 2..33 data, cols 0,1,34,35 zero pads)
#define SIN_FLOATS (68 * 32)          // 2176
#define TMP_STRIDE 37
#define TMP_FLOATS (16 * TMP_STRIDE)  // 592
#define WAVE_FLOATS (SIN_FLOATS + TMP_FLOATS)  // 2768

#define EDGE_SCALE (32.f / 28.f)

__global__ __launch_bounds__(256)
void heatmap_kernel(const float* __restrict__ x,
                    float* __restrict__ out_heat,   // [N,3,16,8]
                    float* __restrict__ out_mr,     // [N,3]
                    float* __restrict__ out_mi) {   // [N,17,2]
    const int n = blockIdx.x;
    const int t = threadIdx.x;
    const int w = t >> 6;    // wave id 0..3
    const int l = t & 63;    // lane

    __shared__ float s_wave[4 * WAVE_FLOATS];   // 44288 B
    __shared__ float s_comb[12 * HW];           // 6144 B  [w*3+g][128]
    __shared__ float s_red[HW];
    __shared__ float s_chmax[N_CH];
    __shared__ float s_bcast;

    float* sw   = s_wave + w * WAVE_FLOATS;
    float* stmp = sw + SIN_FLOATS;

    // zero pad zones once (never overwritten later: channel stores touch only
    // floats [64,2112) of s_in; tmp writes touch only data cols)
    sw[l] = 0.f;            // s_in rows 0,1
    sw[2112 + l] = 0.f;     // s_in rows 66,67
    {
        int r = l >> 2, cc = l & 3;
        int col = (cc < 2) ? cc : (cc + 32);   // {0,1,34,35}
        stmp[r * TMP_STRIDE + col] = 0.f;
    }

    const float W0 = 1.f/32.f, W1 = 3.f/32.f, W2 = 5.f/32.f, W3 = 7.f/32.f;
    const float* xn = x + (size_t)n * N_CH * IN_H * IN_W;
    const int col = l & 31;
    const int rhalf = l >> 5;

    float gl0 = 0.f, gl1 = 0.f, gl2 = 0.f;   // group sums, positions l
    float gh0 = 0.f, gh1 = 0.f, gh2 = 0.f;   // group sums, positions l+64

    float4 bufA[8], bufB[8];
    {   // preload first channel c = w (fully coalesced: 64 lanes x 16B)
        const float4* src = (const float4*)(xn + (size_t)w * IN_H * IN_W);
#pragma unroll
        for (int j = 0; j < 8; ++j) bufA[j] = src[l + 64 * j];
    }

    auto process = [&](float4 (&cur)[8], float4 (&nxt)[8], int c, bool pre) {
        // registers -> s_in data region (contiguous floats [64, 2112))
        float4* dst = (float4*)(sw + 64);
#pragma unroll
        for (int j = 0; j < 8; ++j) dst[l + 64 * j] = cur[j];

        // prefetch next channel for this wave (overlaps both filter stages)
        if (pre) {
            const float4* src = (const float4*)(xn + (size_t)(c + 4) * IN_H * IN_W);
#pragma unroll
            for (int j = 0; j < 8; ++j) nxt[j] = src[l + 64 * j];
        }

        __asm__ __volatile__("" ::: "memory");  // wave-lockstep; stop compiler reorder

        // stage 1: H 64->16 (uniform 8-tap on zero-padded rows, edge rescale)
        float o[8];
#pragma unroll
        for (int k = 0; k < 8; ++k) {
            int r = rhalf * 8 + k;
            const float* b = sw + (4 * r) * 32 + col;
            float acc = W0 * b[0]   + W1 * b[32]  + W2 * b[64]  + W3 * b[96]
                      + W3 * b[128] + W2 * b[160] + W1 * b[192] + W0 * b[224];
            if ((k == 0 && rhalf == 0) || (k == 7 && rhalf == 1)) acc *= EDGE_SCALE;
            o[k] = acc;
        }
        __asm__ __volatile__("" ::: "memory");
#pragma unroll
        for (int k = 0; k < 8; ++k) {
            int r = rhalf * 8 + k;
            stmp[r * TMP_STRIDE + 2 + col] = o[k];
        }
        __asm__ __volatile__("" ::: "memory");

        // stage 2: W 32->8; each lane owns output positions l and l+64
        float out0, out1;
        {
            int r0 = l >> 3, oc = l & 7;
            const float* b0 = stmp + r0 * TMP_STRIDE + 4 * oc;
            out0 = W0*b0[0] + W1*b0[1] + W2*b0[2] + W3*b0[3]
                 + W3*b0[4] + W2*b0[5] + W1*b0[6] + W0*b0[7];
            const float* b1 = b0 + 8 * TMP_STRIDE;
            out1 = W0*b1[0] + W1*b1[1] + W2*b1[2] + W3*b1[3]
                 + W3*b1[4] + W2*b1[5] + W1*b1[6] + W0*b1[7];
            float cs = (oc == 0 || oc == 7) ? EDGE_SCALE : 1.f;
            out0 *= cs; out1 *= cs;
        }

        // per-channel max/argmax (first-max tiebreak), whole wave
        {
            float bv; int bi;
            if (out1 > out0) { bv = out1; bi = l + 64; } else { bv = out0; bi = l; }
#pragma unroll
            for (int off = 32; off >= 1; off >>= 1) {
                float ov = __shfl_down(bv, off);
                int   oi = __shfl_down(bi, off);
                if (ov > bv || (ov == bv && oi < bi)) { bv = ov; bi = oi; }
            }
            if (l == 0) {
                s_chmax[c] = bv;
                float* mi = out_mi + ((size_t)n * N_CH + c) * 2;
                mi[0] = (float)(bi & 7);   // x
                mi[1] = (float)(bi >> 3);  // y
            }
        }

        // group spatial sums (g uniform across wave -> scalar branch)
        int g = (c < 5) ? 0 : ((c < 11) ? 1 : 2);
        if (g == 0)      { gl0 += out0; gh0 += out1; }
        else if (g == 1) { gl1 += out0; gh1 += out1; }
        else             { gl2 += out0; gh2 += out1; }
    };

    // wave w handles channels w, w+4, w+8, ... (no block barriers in this loop)
#pragma unroll
    for (int i = 0; i < 5; ++i) {
        int c = w + 4 * i;
        if (c >= N_CH) break;
        bool pre = (c + 4) < N_CH;
        if (i & 1) process(bufB, bufA, c, pre);
        else       process(bufA, bufB, c, pre);
    }

    // publish per-wave group partials
    s_comb[(w * 3 + 0) * HW + l]      = gl0;
    s_comb[(w * 3 + 0) * HW + l + 64] = gh0;
    s_comb[(w * 3 + 1) * HW + l]      = gl1;
    s_comb[(w * 3 + 1) * HW + l + 64] = gh1;
    s_comb[(w * 3 + 2) * HW + l]      = gl2;
    s_comb[(w * 3 + 2) * HW + l + 64] = gh2;
    __syncthreads();

    // group means of per-channel maxes
    if (t < 3) {
        int lo = (t == 0) ? 0 : ((t == 1) ? 5 : 11);
        int hi = (t == 0) ? 5 : ((t == 1) ? 11 : 17);
        float acc = 0.f;
        for (int c = lo; c < hi; ++c) acc += s_chmax[c];
        out_mr[(size_t)n * 3 + t] = acc / (float)(hi - lo);
    }

    // combine wave partials -> per-position group sums
    float gsv[3] = {0.f, 0.f, 0.f};
    if (t < HW) {
#pragma unroll
        for (int g = 0; g < 3; ++g)
            gsv[g] = s_comb[(0 * 3 + g) * HW + t] + s_comb[(1 * 3 + g) * HW + t]
                   + s_comb[(2 * 3 + g) * HW + t] + s_comb[(3 * 3 + g) * HW + t];
    }

    // softmax over 128 spatial positions, per group
#pragma unroll 1
    for (int g = 0; g < 3; ++g) {
        if (t < HW) s_red[t] = gsv[g];
        __syncthreads();
        if (t < 64) {
            float bv = fmaxf(s_red[t], s_red[t + 64]);
#pragma unroll
            for (int off = 32; off >= 1; off >>= 1)
                bv = fmaxf(bv, __shfl_down(bv, off));
            if (t == 0) s_bcast = bv;
        }
        __syncthreads();
        float m = s_bcast;
        float e = 0.f;
        if (t < HW) { e = expf(gsv[g] - m); s_red[t] = e; }
        __syncthreads();
        if (t < 64) {
            float sv = s_red[t] + s_red[t + 64];
#pragma unroll
            for (int off = 32; off >= 1; off >>= 1)
                sv += __shfl_down(sv, off);
            if (t == 0) s_bcast = sv;
        }
        __syncthreads();
        if (t < HW)
            out_heat[((size_t)n * 3 + g) * HW + t] = e / s_bcast;
        __syncthreads();
    }
}

extern "C" void kernel_launch(void* const* d_in, const int* in_sizes, int n_in,
                              void* d_out, int out_size, void* d_ws, size_t ws_size,
                              hipStream_t stream) {
    const float* x = (const float*)d_in[0];
    float* out = (float*)d_out;
    const int N = in_sizes[0] / (N_CH * IN_H * IN_W);  // 2048
    float* out_heat = out;                             // N*3*128
    float* out_mr   = out_heat + (size_t)N * 3 * HW;   // N*3
    float* out_mi   = out_mr + (size_t)N * 3;          // N*17*2
    heatmap_kernel<<<dim3(N), dim3(256), 0, stream>>>(x, out_heat, out_mr, out_mi);
}